// Round 14
// baseline (244.281 us; speedup 1.0000x reference)
//
#include <hip/hip_runtime.h>
#include <hip/hip_bf16.h>
#include <math.h>

// PaGCN forward, restructured:
//   h0 = relu(AM ⊙ spmm(adjZ, (M⊙x)@W0) + b0)      (spmm gathers 128 bf16 feats)
//   h1 = relu(AM ⊙ spmm(adjZ, (M⊙h0)@W1) + b1)     (spmm gathers 64 bf16 feats)
//   out = log_softmax(spmm(adj, h1@W2) + b2)        (spmm gathers 40 bf16 feats)
//
// R20 (on measured R19 = 241µs): widen ALL gather loads to the row limit.
// R19 proved the gathers are load-ISSUE bound (2-edge uint2 in spmm128_g1
// = -12µs with identical bytes). This round:
//  - spmm128_g1: 4-edge uint4 (16 lanes/edge; 8 loads per 32-edge group vs
//    16; xor-16/32 reduce; lane<16 holds 8 feats -> uint4 LDS write).
//  - spmm64_g2: 8-edge uint4 (8 lanes/edge; 4 loads/32 edges vs 8;
//    xor-8/16/32 reduce; lane<8 -> uint4 LDS write).
//  - spmm40: 6-edge uint2 (10 lanes/edge; 4 loads/24 edges vs 8; cyclic-6
//    rotation reduce b=a+rot30, s=b+rot10(b)+rot20(b); lane<10 holds 4
//    feats; float4 output write).
// Per-edge load instructions halve everywhere; bytes and FMAs unchanged.
// Carried from R18/R19 (measured 241): prep_wt folded away (gemm0 blocks
// self-transpose W0 in LDS; wt1/wt2+gpub prep'd by one extra block),
// XCD-swizzled scatter, LDS-staged MFMA dense layers, sync-free hist+gemm0,
// publish/read-poll scan on distinct addresses, one 16B random store per
// edge, bf16 gather targets, clamped epilogues, HIST_EPB=16384. 6 dispatches.
// Standing lessons: in-kernel flag gates cost 100x a kernel boundary
// (R13/R14); readlane dense GEMM is VALU-bound, use MFMA (R15).

typedef __attribute__((ext_vector_type(8))) short bf16x8;
typedef __attribute__((ext_vector_type(4))) float f32x4;

#define HIST_EPB_LOG 14
#define HIST_EPB 16384          // edges per hist block (< 2^16: u16-safe)
#define NBINS 50176             // >= N, = 196*256, even (u16-pair packing)
#define NBMAX 50                // reserved chunk capacity (E <= 50*16384)
#define SCAN_BLOCKS 196         // 256 bins per block = 50176

__device__ __forceinline__ float rl_f(float v, int j) {
    return __builtin_bit_cast(float,
        __builtin_amdgcn_readlane(__builtin_bit_cast(int, v), j));
}
__device__ __forceinline__ int rl_i(int v, int j) {
    return __builtin_amdgcn_readlane(v, j);
}
__device__ __forceinline__ unsigned short f2bf(float f) {
    unsigned u = __builtin_bit_cast(unsigned, f);
    u += 0x7fffu + ((u >> 16) & 1u);   // round-to-nearest-even
    return (unsigned short)(u >> 16);
}
__device__ __forceinline__ unsigned pack2bf(float lo, float hi) {
    return (unsigned)f2bf(lo) | ((unsigned)f2bf(hi) << 16);
}
__device__ __forceinline__ float bf_lo(unsigned u) {
    return __builtin_bit_cast(float, u << 16);
}
__device__ __forceinline__ float bf_hi(unsigned u) {
    return __builtin_bit_cast(float, u & 0xffff0000u);
}
__device__ __forceinline__ float clampf(float v) {   // NaN -> -1e30 (finite)
    return fminf(fmaxf(v, -1e30f), 1e30f);
}
__device__ __forceinline__ unsigned long long aload(const unsigned long long* p) {
    return __hip_atomic_load(p, __ATOMIC_ACQUIRE, __HIP_MEMORY_SCOPE_AGENT);
}

// ---------------- fused LDS histogram + gemm0 + wt1/wt2 prep ----------------
// Blocks [0,NB): per-chunk LDS histogram over all bins (packed u16 pairs).
// Blocks [NB, NB+gemmB4): gemm0, 4x 256-thread groups; W0 self-transposed
//   into this block's LDS (aliases hcnt) -- no global wt0, no prep gate.
// Block NB+gemmB4: preps wt1/wt2 (global) + zeroes gpub. Consumers are >=2
//   kernel boundaries later -> ordinary kernel-boundary visibility.
// ZERO cross-block synchronization.

__launch_bounds__(1024)
__global__ void hist_gemm0(const int* __restrict__ row,
                           unsigned short* __restrict__ cntmat,
                           unsigned short* __restrict__ lrank, int E, int NB,
                           const float* __restrict__ x, const float* __restrict__ Mv,
                           const float* __restrict__ W0, const float* __restrict__ W1,
                           const float* __restrict__ W2,
                           unsigned short* __restrict__ wt1,
                           unsigned short* __restrict__ wt2,
                           unsigned long long* __restrict__ gpub,
                           unsigned short* __restrict__ t_buf, int n, int gemmB4) {
    __shared__ __align__(16) unsigned hcnt[NBINS / 2];   // 98KB: u16 bin pairs
    const int blk = blockIdx.x;
    const int t = threadIdx.x;
    if (blk < NB) {
        uint4* h4 = (uint4*)hcnt;
        const uint4 z4 = make_uint4(0u, 0u, 0u, 0u);
        for (int i = t; i < NBINS / 8; i += 1024) h4[i] = z4;
        __syncthreads();
        const int s = blk << HIST_EPB_LOG;
        const int e = min(E, s + HIST_EPB);
        for (int i = s + t; i < e; i += 1024) {
            const int r = row[i];               // r < n <= NBINS
            const unsigned sh = (unsigned)(r & 1) << 4;
            const unsigned old = atomicAdd(&hcnt[r >> 1], 1u << sh);
            lrank[i] = (unsigned short)((old >> sh) & 0xffffu);
        }
        __syncthreads();
        uint4* dst = (uint4*)(cntmat + (size_t)blk * NBINS);
        for (int i = t; i < NBINS / 8; i += 1024) dst[i] = h4[i];
    } else if (blk < NB + gemmB4) {
        // ---- gemm0: (M⊙x)@W0 -> t_buf bf16; W0^T staged in LDS ----
        unsigned short* w0l = (unsigned short*)hcnt;     // [128][136] u16, 34.8KB
        const int tid = t & 255;
        const int bid = (blk - NB) * 4 + (t >> 8);
        const int lane = tid & 63;
        const int wid = tid >> 6;
        const int m15 = lane & 15;
        const int q = lane >> 4;
        const int rA = bid * 64 + wid * 16 + m15;

        // A-fragments first (independent of LDS) -- latency hides under transpose
        bf16x8 a[4];
        {
            float m = 1.0f;
            if (rA < n) m = Mv[rA];
#pragma unroll
            for (int ks = 0; ks < 4; ++ks) {
                float4 lo = make_float4(0.f, 0.f, 0.f, 0.f);
                float4 hi = make_float4(0.f, 0.f, 0.f, 0.f);
                if (rA < n) {
                    lo = *(const float4*)(x + (size_t)rA * 128 + ks * 32 + q * 8);
                    hi = *(const float4*)(x + (size_t)rA * 128 + ks * 32 + q * 8 + 4);
                }
                union { bf16x8 v; unsigned short u[8]; } pk;
                pk.u[0] = f2bf(lo.x * m); pk.u[1] = f2bf(lo.y * m);
                pk.u[2] = f2bf(lo.z * m); pk.u[3] = f2bf(lo.w * m);
                pk.u[4] = f2bf(hi.x * m); pk.u[5] = f2bf(hi.y * m);
                pk.u[6] = f2bf(hi.z * m); pk.u[7] = f2bf(hi.w * m);
                a[ks] = pk.v;
            }
        }
        // cooperative W0 transpose: w0l[nn][k] = bf16(W0[k][nn])
#pragma unroll
        for (int i = 0; i < 16; ++i) {
            const int idx = t + i * 1024;                // k-major source
            const int k = idx >> 7, nn = idx & 127;
            w0l[nn * 136 + k] = f2bf(W0[idx]);
        }
        __syncthreads();
#pragma unroll
        for (int nt = 0; nt < 8; ++nt) {
            f32x4 acc = {0.f, 0.f, 0.f, 0.f};
            const int bn = nt * 16 + m15;
#pragma unroll
            for (int ks = 0; ks < 4; ++ks) {
                const uint4 z = *(const uint4*)&w0l[bn * 136 + ks * 32 + q * 8];
                acc = __builtin_amdgcn_mfma_f32_16x16x32_bf16(
                    a[ks], __builtin_bit_cast(bf16x8, z), acc, 0, 0, 0);
            }
            const int gc = nt * 16 + m15;
#pragma unroll
            for (int rr = 0; rr < 4; ++rr) {
                const int gr = bid * 64 + wid * 16 + q * 4 + rr;
                if (gr < n) t_buf[(size_t)gr * 128 + gc] = f2bf(clampf(acc[rr]));
            }
        }
    } else {
        // ---- prep: wt1[64][128], wt2[48][64] (consumed 2+ launches later) ----
        if (t < 256) gpub[t] = 0ULL;
        for (int idx = t; idx < 64 * 128; idx += 1024) {
            int nn = idx >> 7, k = idx & 127;
            wt1[idx] = f2bf(W1[k * 64 + nn]);
        }
        for (int idx = t; idx < 48 * 64; idx += 1024) {
            int nn = idx >> 6, k = idx & 63;
            wt2[idx] = (nn < 40) ? f2bf(W2[k * 40 + nn]) : (unsigned short)0;
        }
    }
}

// ---------------- fused scan: rp + absolute chunk offsets, one kernel ----------------

__launch_bounds__(256)
__global__ void scan_one(const unsigned short* __restrict__ cm,
                         unsigned* __restrict__ cmabs, int* __restrict__ rp,
                         unsigned long long* __restrict__ gpub,
                         int n, int NB, int E) {
    __shared__ int sd[256];
    const int g = blockIdx.x;
    const int t = threadIdx.x;
    const int bin = g * 256 + t;

    unsigned tot = 0;
    for (int b = 0; b < NB; ++b) tot += cm[(size_t)b * NBINS + bin];

    sd[t] = (int)tot;
    __syncthreads();
    for (int off = 1; off < 256; off <<= 1) {
        int xv = (t >= off) ? sd[t - off] : 0;
        __syncthreads();
        sd[t] += xv;
        __syncthreads();
    }
    const int excl = sd[t] - (int)tot;
    const int gtot = sd[255];
    __syncthreads();

    if (t == 0)
        atomicExch(&gpub[g], (1ULL << 32) | (unsigned long long)(unsigned)gtot);

    int my = 0;
    for (int p = t; p < g; p += 256) {
        unsigned long long v;
        do { v = aload(&gpub[p]); } while ((v >> 32) == 0ULL);
        my += (int)(unsigned)v;
    }
    sd[t] = my;
    __syncthreads();
    for (int off = 128; off > 0; off >>= 1) {
        if (t < off) sd[t] += sd[t + off];
        __syncthreads();
    }
    const int base = sd[0];

    const int rpf = base + excl;
    if (bin < n) rp[bin] = rpf;
    if (g == SCAN_BLOCKS - 1 && t == 255) rp[n] = E;

    int run = rpf;
    for (int b = 0; b < NB; ++b) {
        cmabs[(size_t)b * NBINS + bin] = (unsigned)run;
        run += (int)cm[(size_t)b * NBINS + bin];
    }
}

// ---------------- scatter (atomic-free, ONE random 16B line per edge) ----------------
// XCD-swizzled grid: chunk c's blocks share residue mod 8 -> one XCD owns
// c's 200KB cmabs row (heuristic; correctness mapping-independent).

__launch_bounds__(256)
__global__ void scatter_kernel(const int* __restrict__ row, const int* __restrict__ col,
                               const float* __restrict__ vA, const float* __restrict__ vZ,
                               const unsigned* __restrict__ cmabs,
                               const unsigned short* __restrict__ lrank,
                               uint4* __restrict__ packed16, int E, int NB) {
    const int p = blockIdx.x;
    const int c = (p & 7) + 8 * (p >> 9);       // chunk (8 chunks / 512 blocks)
    if (c >= NB) return;
    const int o = (p >> 3) & 63;                // block within chunk (64x256=16384)
    const int e = (c << HIST_EPB_LOG) + o * 256 + threadIdx.x;
    if (e >= E) return;
    const int r = row[e];
    const int pos = (int)(cmabs[(size_t)c * NBINS + r] + (unsigned)lrank[e]);
    uint4 pk;
    pk.x = (unsigned)col[e];
    pk.y = __builtin_bit_cast(unsigned, vZ[e]);
    pk.z = __builtin_bit_cast(unsigned, vA[e]);
    pk.w = 0u;
    packed16[pos] = pk;
}

// ---------------- SpMM F=128 + MFMA gemm1: g1 = (M⊙h0)@W1 ----------------
// Block = 16 rows: 4 waves x 4 rows. Gather = 4-edge-parallel uint4:
// slot g4=lane>>4 owns edges j+4q+g4; lane reads 8 feats (16B) at
// ls=lane&15. xor-16/32 merges slots. Epilogue -> LDS h16[16][136] bf16.
// Barrier. Wave w computes output cols w*16.. via 4 MFMAs.

__launch_bounds__(256)
__global__ void spmm128_g1(const uint4* __restrict__ packed16,
                           const int* __restrict__ rp, const unsigned short* __restrict__ X,
                           const float* __restrict__ AM, const float* __restrict__ Mv,
                           const float* __restrict__ bias,
                           const unsigned short* __restrict__ wt1,
                           unsigned short* __restrict__ g1, int n) {
    __shared__ __align__(16) unsigned short h16[16][136];
    const int t = threadIdx.x;
    const int lane = t & 63;
    const int w = t >> 6;
    const int g4 = lane >> 4;       // edge slot 0..3
    const int ls = lane & 15;       // feat octet: feats 8*ls..8*ls+7
    const int rbase = blockIdx.x * 16;

    for (int i = 0; i < 4; ++i) {
        const int lr = w * 4 + i;
        const int r = rbase + lr;
        float a0 = 0.f, a1 = 0.f, a2 = 0.f, a3 = 0.f;
        float a4 = 0.f, a5 = 0.f, a6 = 0.f, a7 = 0.f;
        if (r < n) {
            const int s = __builtin_amdgcn_readfirstlane(rp[r]);
            const int e = __builtin_amdgcn_readfirstlane(rp[r + 1]);
            for (int base = s; base < e; base += 64) {
                const int nn = min(64, e - base);
                int ci = 0; float vf = 0.0f;
                if (lane < nn) {
                    const uint4 pk = packed16[base + lane];
                    ci = (int)pk.x;
                    vf = __builtin_bit_cast(float, pk.y);
                }
                for (int j = 0; j < nn; j += 32) {   // 8 uint4 loads in flight
                    uint4 uu[8]; float vv[8];
#pragma unroll
                    for (int q = 0; q < 8; ++q) {
                        const int jj = j + 4 * q + g4;
                        const bool ok = jj < nn;
                        const int idx = jj & 63;
                        const int c = __shfl(ci, idx);
                        const float v = __shfl(vf, idx);
                        vv[q] = ok ? v : 0.0f;
                        uint4 u = make_uint4(0u, 0u, 0u, 0u);
                        if (ok) u = *(const uint4*)(X + (size_t)c * 128 + ls * 8);
                        uu[q] = u;
                    }
#pragma unroll
                    for (int q = 0; q < 8; ++q) {
                        a0 += vv[q] * bf_lo(uu[q].x);
                        a1 += vv[q] * bf_hi(uu[q].x);
                        a2 += vv[q] * bf_lo(uu[q].y);
                        a3 += vv[q] * bf_hi(uu[q].y);
                        a4 += vv[q] * bf_lo(uu[q].z);
                        a5 += vv[q] * bf_hi(uu[q].z);
                        a6 += vv[q] * bf_lo(uu[q].w);
                        a7 += vv[q] * bf_hi(uu[q].w);
                    }
                }
            }
            a0 += __shfl_xor(a0, 16); a0 += __shfl_xor(a0, 32);
            a1 += __shfl_xor(a1, 16); a1 += __shfl_xor(a1, 32);
            a2 += __shfl_xor(a2, 16); a2 += __shfl_xor(a2, 32);
            a3 += __shfl_xor(a3, 16); a3 += __shfl_xor(a3, 32);
            a4 += __shfl_xor(a4, 16); a4 += __shfl_xor(a4, 32);
            a5 += __shfl_xor(a5, 16); a5 += __shfl_xor(a5, 32);
            a6 += __shfl_xor(a6, 16); a6 += __shfl_xor(a6, 32);
            a7 += __shfl_xor(a7, 16); a7 += __shfl_xor(a7, 32);
            const float am = AM[r];
            const float mr = Mv[r];   // fold M (>=0): M⊙relu(y) = relu(M⊙y)
            a0 = fminf(fmaxf((a0 * am + bias[8 * ls + 0]) * mr, 0.0f), 1e30f);
            a1 = fminf(fmaxf((a1 * am + bias[8 * ls + 1]) * mr, 0.0f), 1e30f);
            a2 = fminf(fmaxf((a2 * am + bias[8 * ls + 2]) * mr, 0.0f), 1e30f);
            a3 = fminf(fmaxf((a3 * am + bias[8 * ls + 3]) * mr, 0.0f), 1e30f);
            a4 = fminf(fmaxf((a4 * am + bias[8 * ls + 4]) * mr, 0.0f), 1e30f);
            a5 = fminf(fmaxf((a5 * am + bias[8 * ls + 5]) * mr, 0.0f), 1e30f);
            a6 = fminf(fmaxf((a6 * am + bias[8 * ls + 6]) * mr, 0.0f), 1e30f);
            a7 = fminf(fmaxf((a7 * am + bias[8 * ls + 7]) * mr, 0.0f), 1e30f);
        }
        if (lane < 16) {
            uint4 wv;
            wv.x = pack2bf(a0, a1);
            wv.y = pack2bf(a2, a3);
            wv.z = pack2bf(a4, a5);
            wv.w = pack2bf(a6, a7);
            *(uint4*)&h16[lr][8 * ls] = wv;
        }
    }
    __syncthreads();

    // MFMA gemm1: wave w -> cols w*16 .. w*16+15
    const int m15 = lane & 15;
    const int q = lane >> 4;
    bf16x8 a[4];
#pragma unroll
    for (int ks = 0; ks < 4; ++ks)
        a[ks] = __builtin_bit_cast(bf16x8,
                    *(const uint4*)&h16[m15][ks * 32 + q * 8]);
    f32x4 acc = {0.f, 0.f, 0.f, 0.f};
    const int bn = w * 16 + m15;
#pragma unroll
    for (int ks = 0; ks < 4; ++ks) {
        const uint4 z = *(const uint4*)(wt1 + (size_t)bn * 128 + ks * 32 + q * 8);
        acc = __builtin_amdgcn_mfma_f32_16x16x32_bf16(
            a[ks], __builtin_bit_cast(bf16x8, z), acc, 0, 0, 0);
    }
    const int gcol = w * 16 + m15;
#pragma unroll
    for (int rr = 0; rr < 4; ++rr) {
        const int grow = rbase + q * 4 + rr;
        if (grow < n) g1[(size_t)grow * 64 + gcol] = f2bf(clampf(acc[rr]));
    }
}

// ---------------- SpMM F=64 + MFMA gemm2: out40 = relu(AM⊙agg+b1)@W2 ----------------
// Block = 16 rows: 4 waves x 4 rows. Gather = 8-edge-parallel uint4:
// slot g8=lane>>3 owns edges j+8q+g8; lane reads 8 feats (16B) at
// ls=lane&7. xor-8/16/32 merges slots. lane<8 -> uint4 LDS write. Barrier.
// Waves 0-2 compute col-tiles (48 padded cols, 2 MFMAs); write cols<40.

__launch_bounds__(256)
__global__ void spmm64_g2(const uint4* __restrict__ packed16,
                          const int* __restrict__ rp, const unsigned short* __restrict__ X,
                          const float* __restrict__ AM, const float* __restrict__ bias1,
                          const unsigned short* __restrict__ wt2,
                          unsigned short* __restrict__ out40, int n) {
    __shared__ __align__(16) unsigned short h16[16][72];
    const int t = threadIdx.x;
    const int lane = t & 63;
    const int w = t >> 6;
    const int g8 = lane >> 3;       // edge slot 0..7
    const int ls = lane & 7;        // feat octet: feats 8*ls..8*ls+7
    const int rbase = blockIdx.x * 16;

    for (int i = 0; i < 4; ++i) {
        const int lr = w * 4 + i;
        const int r = rbase + lr;
        float a0 = 0.f, a1 = 0.f, a2 = 0.f, a3 = 0.f;
        float a4 = 0.f, a5 = 0.f, a6 = 0.f, a7 = 0.f;
        if (r < n) {
            const int s = __builtin_amdgcn_readfirstlane(rp[r]);
            const int e = __builtin_amdgcn_readfirstlane(rp[r + 1]);
            for (int base = s; base < e; base += 64) {
                const int nn = min(64, e - base);
                int ci = 0; float vf = 0.0f;
                if (lane < nn) {
                    const uint4 pk = packed16[base + lane];
                    ci = (int)pk.x;
                    vf = __builtin_bit_cast(float, pk.y);
                }
                for (int j = 0; j < nn; j += 32) {   // 4 uint4 loads in flight
                    uint4 uu[4]; float vv[4];
#pragma unroll
                    for (int q = 0; q < 4; ++q) {
                        const int jj = j + 8 * q + g8;
                        const bool ok = jj < nn;
                        const int idx = jj & 63;
                        const int c = __shfl(ci, idx);
                        const float v = __shfl(vf, idx);
                        vv[q] = ok ? v : 0.0f;
                        uint4 u = make_uint4(0u, 0u, 0u, 0u);
                        if (ok) u = *(const uint4*)(X + (size_t)c * 64 + ls * 8);
                        uu[q] = u;
                    }
#pragma unroll
                    for (int q = 0; q < 4; ++q) {
                        a0 += vv[q] * bf_lo(uu[q].x);
                        a1 += vv[q] * bf_hi(uu[q].x);
                        a2 += vv[q] * bf_lo(uu[q].y);
                        a3 += vv[q] * bf_hi(uu[q].y);
                        a4 += vv[q] * bf_lo(uu[q].z);
                        a5 += vv[q] * bf_hi(uu[q].z);
                        a6 += vv[q] * bf_lo(uu[q].w);
                        a7 += vv[q] * bf_hi(uu[q].w);
                    }
                }
            }
            a0 += __shfl_xor(a0, 8); a0 += __shfl_xor(a0, 16); a0 += __shfl_xor(a0, 32);
            a1 += __shfl_xor(a1, 8); a1 += __shfl_xor(a1, 16); a1 += __shfl_xor(a1, 32);
            a2 += __shfl_xor(a2, 8); a2 += __shfl_xor(a2, 16); a2 += __shfl_xor(a2, 32);
            a3 += __shfl_xor(a3, 8); a3 += __shfl_xor(a3, 16); a3 += __shfl_xor(a3, 32);
            a4 += __shfl_xor(a4, 8); a4 += __shfl_xor(a4, 16); a4 += __shfl_xor(a4, 32);
            a5 += __shfl_xor(a5, 8); a5 += __shfl_xor(a5, 16); a5 += __shfl_xor(a5, 32);
            a6 += __shfl_xor(a6, 8); a6 += __shfl_xor(a6, 16); a6 += __shfl_xor(a6, 32);
            a7 += __shfl_xor(a7, 8); a7 += __shfl_xor(a7, 16); a7 += __shfl_xor(a7, 32);
            const float am = AM[r];
            a0 = fminf(fmaxf(a0 * am + bias1[8 * ls + 0], 0.0f), 1e30f);
            a1 = fminf(fmaxf(a1 * am + bias1[8 * ls + 1], 0.0f), 1e30f);
            a2 = fminf(fmaxf(a2 * am + bias1[8 * ls + 2], 0.0f), 1e30f);
            a3 = fminf(fmaxf(a3 * am + bias1[8 * ls + 3], 0.0f), 1e30f);
            a4 = fminf(fmaxf(a4 * am + bias1[8 * ls + 4], 0.0f), 1e30f);
            a5 = fminf(fmaxf(a5 * am + bias1[8 * ls + 5], 0.0f), 1e30f);
            a6 = fminf(fmaxf(a6 * am + bias1[8 * ls + 6], 0.0f), 1e30f);
            a7 = fminf(fmaxf(a7 * am + bias1[8 * ls + 7], 0.0f), 1e30f);
        }
        if (lane < 8) {
            uint4 wv;
            wv.x = pack2bf(a0, a1);
            wv.y = pack2bf(a2, a3);
            wv.z = pack2bf(a4, a5);
            wv.w = pack2bf(a6, a7);
            *(uint4*)&h16[lr][8 * ls] = wv;
        }
    }
    __syncthreads();

    // MFMA gemm2: waves 0-2 -> col tiles 0..2 (cols 0..47, wt2 zero-padded)
    if (w < 3) {
        const int m15 = lane & 15;
        const int q = lane >> 4;
        bf16x8 a[2];
#pragma unroll
        for (int ks = 0; ks < 2; ++ks)
            a[ks] = __builtin_bit_cast(bf16x8,
                        *(const uint4*)&h16[m15][ks * 32 + q * 8]);
        f32x4 acc = {0.f, 0.f, 0.f, 0.f};
        const int bn = w * 16 + m15;
#pragma unroll
        for (int ks = 0; ks < 2; ++ks) {
            const uint4 z = *(const uint4*)(wt2 + (size_t)bn * 64 + ks * 32 + q * 8);
            acc = __builtin_amdgcn_mfma_f32_16x16x32_bf16(
                a[ks], __builtin_bit_cast(bf16x8, z), acc, 0, 0, 0);
        }
        const int gcol = w * 16 + m15;
        if (gcol < 40) {
#pragma unroll
            for (int rr = 0; rr < 4; ++rr) {
                const int grow = rbase + q * 4 + rr;
                if (grow < n) out40[(size_t)grow * 40 + gcol] = f2bf(clampf(acc[rr]));
            }
        }
    }
}

// ---------------- SpMM F=40 + log_softmax: 6 edges/wave (uint2/lane) ----------------
// Slot g6=lane/10 (lanes 60-63 idle) owns edges j+6q+g6; lane reads 4 feats
// (8B) at ls=lane%10. Cyclic-6 reduce: b=a+rot30(a); s=b+rot10(b)+rot20(b).
// lane<10 holds 4 feats -> float4 output write after log_softmax.

__launch_bounds__(256)
__global__ void spmm40_kernel(const uint4* __restrict__ packed16,
                              const int* __restrict__ rp, const unsigned short* __restrict__ X,
                              const float* __restrict__ bias,
                              float* __restrict__ out, int n) {
    const int lane = threadIdx.x & 63;
    const int g6 = lane / 10;
    const int ls = lane - 10 * g6;
    const bool active = g6 < 6;
    const int rot30 = (lane + 30 < 60) ? lane + 30 : lane - 30;
    const int rot10 = (lane + 10 < 60) ? lane + 10 : lane - 50;
    const int rot20 = (lane + 20 < 60) ? lane + 20 : lane - 40;
    const int r = (int)((blockIdx.x * (unsigned)blockDim.x + threadIdx.x) >> 6);
    if (r >= n) return;
    const int s = __builtin_amdgcn_readfirstlane(rp[r]);
    const int e = __builtin_amdgcn_readfirstlane(rp[r + 1]);

    float a0 = 0.f, a1 = 0.f, a2 = 0.f, a3 = 0.f;
    for (int base = s; base < e; base += 64) {
        const int nn = min(64, e - base);
        int ci = 0; float vf = 0.0f;
        if (lane < nn) {
            const uint4 pk = packed16[base + lane];
            ci = (int)pk.x;
            vf = __builtin_bit_cast(float, pk.z);    // adj (not adjZ) values
        }
        for (int j = 0; j < nn; j += 24) {   // 4 uint2 loads in flight
            uint2 uu[4]; float vv[4];
#pragma unroll
            for (int q = 0; q < 4; ++q) {
                const int jj = j + 6 * q + g6;
                const bool ok = active && jj < nn;
                const int idx = jj & 63;
                const int c = __shfl(ci, idx);
                const float v = __shfl(vf, idx);
                vv[q] = ok ? v : 0.0f;
                uint2 u = make_uint2(0u, 0u);
                if (ok) u = *(const uint2*)(X + (size_t)c * 40 + ls * 4);
                uu[q] = u;
            }
#pragma unroll
            for (int q = 0; q < 4; ++q) {
                a0 += vv[q] * bf_lo(uu[q].x);
                a1 += vv[q] * bf_hi(uu[q].x);
                a2 += vv[q] * bf_lo(uu[q].y);
                a3 += vv[q] * bf_hi(uu[q].y);
            }
        }
    }
    // cyclic-6 reduce: b(g) = a(g)+a(g+3); s(g) = b(g)+b(g+1)+b(g+2) = total
    float b0 = a0 + __shfl(a0, rot30);
    float b1 = a1 + __shfl(a1, rot30);
    float b2 = a2 + __shfl(a2, rot30);
    float b3 = a3 + __shfl(a3, rot30);
    a0 = b0 + __shfl(b0, rot10) + __shfl(b0, rot20);
    a1 = b1 + __shfl(b1, rot10) + __shfl(b1, rot20);
    a2 = b2 + __shfl(b2, rot10) + __shfl(b2, rot20);
    a3 = b3 + __shfl(b3, rot10) + __shfl(b3, rot20);

    const bool own = lane < 10;
    const float v0 = own ? fminf(fmaxf(a0 + bias[4 * ls + 0], -1e30f), 1e30f) : -INFINITY;
    const float v1 = own ? fminf(fmaxf(a1 + bias[4 * ls + 1], -1e30f), 1e30f) : -INFINITY;
    const float v2 = own ? fminf(fmaxf(a2 + bias[4 * ls + 2], -1e30f), 1e30f) : -INFINITY;
    const float v3 = own ? fminf(fmaxf(a3 + bias[4 * ls + 3], -1e30f), 1e30f) : -INFINITY;
    float mx = fmaxf(fmaxf(v0, v1), fmaxf(v2, v3));
#pragma unroll
    for (int off = 32; off > 0; off >>= 1) mx = fmaxf(mx, __shfl_xor(mx, off));
    float sum = own ? (expf(v0 - mx) + expf(v1 - mx) + expf(v2 - mx) + expf(v3 - mx))
                    : 0.0f;
#pragma unroll
    for (int off = 32; off > 0; off >>= 1) sum += __shfl_xor(sum, off);
    if (own) {
        const float lse = mx + logf(sum);
        float4 o;
        o.x = v0 - lse; o.y = v1 - lse; o.z = v2 - lse; o.w = v3 - lse;
        *(float4*)(out + (size_t)r * 40 + ls * 4) = o;
    }
}

// ---------------- launch ----------------

extern "C" void kernel_launch(void* const* d_in, const int* in_sizes, int n_in,
                              void* d_out, int out_size, void* d_ws, size_t ws_size,
                              hipStream_t stream) {
    const float* x    = (const float*)d_in[0];
    const float* M    = (const float*)d_in[1];
    const float* AM   = (const float*)d_in[2];
    const float* adjv = (const float*)d_in[3];
    const float* adjZ = (const float*)d_in[4];
    const float* W0   = (const float*)d_in[5];
    const float* b0   = (const float*)d_in[6];
    const float* W1   = (const float*)d_in[7];
    const float* b1   = (const float*)d_in[8];
    const float* W2   = (const float*)d_in[9];
    const float* b2   = (const float*)d_in[10];
    const int* row    = (const int*)d_in[11];
    const int* col    = (const int*)d_in[12];
    float* out = (float*)d_out;

    const int n = in_sizes[1];   // N  (must be <= NBINS = 50176)
    const int E = in_sizes[3];   // edges (<= NBMAX*16384)

    // workspace layout (~55 MB, NO aliasing):
    unsigned short* t_buf = (unsigned short*)d_ws;          // N*128 bf16
    unsigned short* wt1 = t_buf + (size_t)n * 128;          // 64*128
    unsigned short* wt2 = wt1 + 64 * 128;                   // 48*64
    unsigned short* h_buf = wt2 + 48 * 64;                  // N*128 bf16
    int* rp = (int*)(h_buf + (size_t)n * 128);              // N+1 (+pad)
    unsigned long long* gpub = (unsigned long long*)
        (((uintptr_t)(rp + n + 2) + 7) & ~(uintptr_t)7);    // 256 u64
    uint4* packed16 = (uint4*)
        (((uintptr_t)(gpub + 256) + 15) & ~(uintptr_t)15);  // E uint4
    unsigned short* lrank = (unsigned short*)(packed16 + (size_t)E);   // E u16
    unsigned short* cntmat = lrank + (size_t)E;             // [NBMAX][NBINS] u16
    unsigned* cmabs = (unsigned*)(cntmat + (size_t)NBMAX * NBINS);     // u32

    const int NB = (E + HIST_EPB - 1) >> HIST_EPB_LOG;      // hist chunks (<=49)
    const int gemmBlocks = (n + 63) / 64;                   // 4-wave gemm groups
    const int gemmB4 = (gemmBlocks + 3) / 4;                // 1024-thr gemm blocks
    // grid NB + gemmB4 + 1 must stay <= 256 (one block-wave at 98KB LDS)

    // fused LDS histogram + gemm0 (W0 self-transposed) + wt1/wt2/gpub prep
    hist_gemm0<<<NB + gemmB4 + 1, 1024, 0, stream>>>(row, cntmat, lrank, E, NB,
                                                     x, M, W0, W1, W2,
                                                     wt1, wt2, gpub, t_buf, n,
                                                     gemmB4);

    // one-kernel scan: rp + absolute chunk offsets (publish/read-poll)
    scan_one<<<SCAN_BLOCKS, 256, 0, stream>>>(cntmat, cmabs, rp, gpub, n, NB, E);

    // scatter, XCD-swizzled (one 16B random store per edge)
    const int scatGrid = 512 * ((NB + 7) / 8);
    scatter_kernel<<<scatGrid, 256, 0, stream>>>(row, col, adjv, adjZ,
                                                 cmabs, lrank, packed16, E, NB);

    const int blk16 = (n + 15) / 16;   // 16 rows per block

    // layer 0 aggregate + MFMA gemm1: h_buf(stride 64) = (M⊙h0)@W1
    spmm128_g1<<<blk16, 256, 0, stream>>>(packed16, rp, t_buf, AM, M, b0, wt1,
                                          h_buf, n);
    // layer 1 aggregate + MFMA gemm2: t_buf(stride 40) = relu(AM⊙agg+b1)@W2
    spmm64_g2<<<blk16, 256, 0, stream>>>(packed16, rp, h_buf, AM, b1, wt2,
                                         t_buf, n);
    // layer 2 aggregate + log_softmax
    spmm40_kernel<<<blk16 * 4, 256, 0, stream>>>(packed16, rp, t_buf, b2, out, n);
}

// Round 16
// 234.773 us; speedup vs baseline: 1.0405x; 1.0405x over previous
//
#include <hip/hip_runtime.h>
#include <hip/hip_bf16.h>
#include <math.h>

// PaGCN forward, restructured:
//   h0 = relu(AM ⊙ spmm(adjZ, (M⊙x)@W0) + b0)      (spmm gathers 128 bf16 feats)
//   h1 = relu(AM ⊙ spmm(adjZ, (M⊙h0)@W1) + b1)     (spmm gathers 64 bf16 feats)
//   out = log_softmax(spmm(adj, h1@W2) + b2)        (spmm gathers 40 bf16 feats)
//
// R22 (recovery; R21's tiered unmasked gathers core-dumped -- unproven
// construct, reverted). This round composes ONLY measured-passing pieces:
//  - front half (hist_gemm0/scan_one/scatter): unchanged since R18
//    (passed 253/241/244).
//  - spmm128_g1: R19's 2-edge uint2 gather (R19 = 241µs, measured best;
//    R20's uint4 g1 was VALU-bound on masked waste and regressed).
//  - spmm64_g2: R20's 8-edge uint4 gather (R20 passed; g2+spmm40
//    widenings were the net-positive part of R20).
//  - spmm40: R20's 6-edge uint2 cyclic-reduce version.
// Predicted: R19's 241 + R20's g2/40 gains => ~234-237µs.
// Standing lessons: in-kernel flag gates cost 100x a kernel boundary
// (R13/R14); readlane dense GEMM is VALU-bound, use MFMA (R15); gather
// slot width peaks at uint2 for deg-16 F=128 rows (R19/R20); don't ship
// unproven gather structures without a fallback (R21).

typedef __attribute__((ext_vector_type(8))) short bf16x8;
typedef __attribute__((ext_vector_type(4))) float f32x4;

#define HIST_EPB_LOG 14
#define HIST_EPB 16384          // edges per hist block (< 2^16: u16-safe)
#define NBINS 50176             // >= N, = 196*256, even (u16-pair packing)
#define NBMAX 50                // reserved chunk capacity (E <= 50*16384)
#define SCAN_BLOCKS 196         // 256 bins per block = 50176

__device__ __forceinline__ float rl_f(float v, int j) {
    return __builtin_bit_cast(float,
        __builtin_amdgcn_readlane(__builtin_bit_cast(int, v), j));
}
__device__ __forceinline__ int rl_i(int v, int j) {
    return __builtin_amdgcn_readlane(v, j);
}
__device__ __forceinline__ unsigned short f2bf(float f) {
    unsigned u = __builtin_bit_cast(unsigned, f);
    u += 0x7fffu + ((u >> 16) & 1u);   // round-to-nearest-even
    return (unsigned short)(u >> 16);
}
__device__ __forceinline__ unsigned pack2bf(float lo, float hi) {
    return (unsigned)f2bf(lo) | ((unsigned)f2bf(hi) << 16);
}
__device__ __forceinline__ float bf_lo(unsigned u) {
    return __builtin_bit_cast(float, u << 16);
}
__device__ __forceinline__ float bf_hi(unsigned u) {
    return __builtin_bit_cast(float, u & 0xffff0000u);
}
__device__ __forceinline__ float clampf(float v) {   // NaN -> -1e30 (finite)
    return fminf(fmaxf(v, -1e30f), 1e30f);
}
__device__ __forceinline__ unsigned long long aload(const unsigned long long* p) {
    return __hip_atomic_load(p, __ATOMIC_ACQUIRE, __HIP_MEMORY_SCOPE_AGENT);
}

// ---------------- fused LDS histogram + gemm0 + wt1/wt2 prep ----------------
// Blocks [0,NB): per-chunk LDS histogram over all bins (packed u16 pairs).
// Blocks [NB, NB+gemmB4): gemm0, 4x 256-thread groups; W0 self-transposed
//   into this block's LDS (aliases hcnt) -- no global wt0, no prep gate.
// Block NB+gemmB4: preps wt1/wt2 (global) + zeroes gpub. Consumers are >=2
//   kernel boundaries later -> ordinary kernel-boundary visibility.
// ZERO cross-block synchronization.

__launch_bounds__(1024)
__global__ void hist_gemm0(const int* __restrict__ row,
                           unsigned short* __restrict__ cntmat,
                           unsigned short* __restrict__ lrank, int E, int NB,
                           const float* __restrict__ x, const float* __restrict__ Mv,
                           const float* __restrict__ W0, const float* __restrict__ W1,
                           const float* __restrict__ W2,
                           unsigned short* __restrict__ wt1,
                           unsigned short* __restrict__ wt2,
                           unsigned long long* __restrict__ gpub,
                           unsigned short* __restrict__ t_buf, int n, int gemmB4) {
    __shared__ __align__(16) unsigned hcnt[NBINS / 2];   // 98KB: u16 bin pairs
    const int blk = blockIdx.x;
    const int t = threadIdx.x;
    if (blk < NB) {
        uint4* h4 = (uint4*)hcnt;
        const uint4 z4 = make_uint4(0u, 0u, 0u, 0u);
        for (int i = t; i < NBINS / 8; i += 1024) h4[i] = z4;
        __syncthreads();
        const int s = blk << HIST_EPB_LOG;
        const int e = min(E, s + HIST_EPB);
        for (int i = s + t; i < e; i += 1024) {
            const int r = row[i];               // r < n <= NBINS
            const unsigned sh = (unsigned)(r & 1) << 4;
            const unsigned old = atomicAdd(&hcnt[r >> 1], 1u << sh);
            lrank[i] = (unsigned short)((old >> sh) & 0xffffu);
        }
        __syncthreads();
        uint4* dst = (uint4*)(cntmat + (size_t)blk * NBINS);
        for (int i = t; i < NBINS / 8; i += 1024) dst[i] = h4[i];
    } else if (blk < NB + gemmB4) {
        // ---- gemm0: (M⊙x)@W0 -> t_buf bf16; W0^T staged in LDS ----
        unsigned short* w0l = (unsigned short*)hcnt;     // [128][136] u16, 34.8KB
        const int tid = t & 255;
        const int bid = (blk - NB) * 4 + (t >> 8);
        const int lane = tid & 63;
        const int wid = tid >> 6;
        const int m15 = lane & 15;
        const int q = lane >> 4;
        const int rA = bid * 64 + wid * 16 + m15;

        // A-fragments first (independent of LDS) -- latency hides under transpose
        bf16x8 a[4];
        {
            float m = 1.0f;
            if (rA < n) m = Mv[rA];
#pragma unroll
            for (int ks = 0; ks < 4; ++ks) {
                float4 lo = make_float4(0.f, 0.f, 0.f, 0.f);
                float4 hi = make_float4(0.f, 0.f, 0.f, 0.f);
                if (rA < n) {
                    lo = *(const float4*)(x + (size_t)rA * 128 + ks * 32 + q * 8);
                    hi = *(const float4*)(x + (size_t)rA * 128 + ks * 32 + q * 8 + 4);
                }
                union { bf16x8 v; unsigned short u[8]; } pk;
                pk.u[0] = f2bf(lo.x * m); pk.u[1] = f2bf(lo.y * m);
                pk.u[2] = f2bf(lo.z * m); pk.u[3] = f2bf(lo.w * m);
                pk.u[4] = f2bf(hi.x * m); pk.u[5] = f2bf(hi.y * m);
                pk.u[6] = f2bf(hi.z * m); pk.u[7] = f2bf(hi.w * m);
                a[ks] = pk.v;
            }
        }
        // cooperative W0 transpose: w0l[nn][k] = bf16(W0[k][nn])
#pragma unroll
        for (int i = 0; i < 16; ++i) {
            const int idx = t + i * 1024;                // k-major source
            const int k = idx >> 7, nn = idx & 127;
            w0l[nn * 136 + k] = f2bf(W0[idx]);
        }
        __syncthreads();
#pragma unroll
        for (int nt = 0; nt < 8; ++nt) {
            f32x4 acc = {0.f, 0.f, 0.f, 0.f};
            const int bn = nt * 16 + m15;
#pragma unroll
            for (int ks = 0; ks < 4; ++ks) {
                const uint4 z = *(const uint4*)&w0l[bn * 136 + ks * 32 + q * 8];
                acc = __builtin_amdgcn_mfma_f32_16x16x32_bf16(
                    a[ks], __builtin_bit_cast(bf16x8, z), acc, 0, 0, 0);
            }
            const int gc = nt * 16 + m15;
#pragma unroll
            for (int rr = 0; rr < 4; ++rr) {
                const int gr = bid * 64 + wid * 16 + q * 4 + rr;
                if (gr < n) t_buf[(size_t)gr * 128 + gc] = f2bf(clampf(acc[rr]));
            }
        }
    } else {
        // ---- prep: wt1[64][128], wt2[48][64] (consumed 2+ launches later) ----
        if (t < 256) gpub[t] = 0ULL;
        for (int idx = t; idx < 64 * 128; idx += 1024) {
            int nn = idx >> 7, k = idx & 127;
            wt1[idx] = f2bf(W1[k * 64 + nn]);
        }
        for (int idx = t; idx < 48 * 64; idx += 1024) {
            int nn = idx >> 6, k = idx & 63;
            wt2[idx] = (nn < 40) ? f2bf(W2[k * 40 + nn]) : (unsigned short)0;
        }
    }
}

// ---------------- fused scan: rp + absolute chunk offsets, one kernel ----------------

__launch_bounds__(256)
__global__ void scan_one(const unsigned short* __restrict__ cm,
                         unsigned* __restrict__ cmabs, int* __restrict__ rp,
                         unsigned long long* __restrict__ gpub,
                         int n, int NB, int E) {
    __shared__ int sd[256];
    const int g = blockIdx.x;
    const int t = threadIdx.x;
    const int bin = g * 256 + t;

    unsigned tot = 0;
    for (int b = 0; b < NB; ++b) tot += cm[(size_t)b * NBINS + bin];

    sd[t] = (int)tot;
    __syncthreads();
    for (int off = 1; off < 256; off <<= 1) {
        int xv = (t >= off) ? sd[t - off] : 0;
        __syncthreads();
        sd[t] += xv;
        __syncthreads();
    }
    const int excl = sd[t] - (int)tot;
    const int gtot = sd[255];
    __syncthreads();

    if (t == 0)
        atomicExch(&gpub[g], (1ULL << 32) | (unsigned long long)(unsigned)gtot);

    int my = 0;
    for (int p = t; p < g; p += 256) {
        unsigned long long v;
        do { v = aload(&gpub[p]); } while ((v >> 32) == 0ULL);
        my += (int)(unsigned)v;
    }
    sd[t] = my;
    __syncthreads();
    for (int off = 128; off > 0; off >>= 1) {
        if (t < off) sd[t] += sd[t + off];
        __syncthreads();
    }
    const int base = sd[0];

    const int rpf = base + excl;
    if (bin < n) rp[bin] = rpf;
    if (g == SCAN_BLOCKS - 1 && t == 255) rp[n] = E;

    int run = rpf;
    for (int b = 0; b < NB; ++b) {
        cmabs[(size_t)b * NBINS + bin] = (unsigned)run;
        run += (int)cm[(size_t)b * NBINS + bin];
    }
}

// ---------------- scatter (atomic-free, ONE random 16B line per edge) ----------------
// XCD-swizzled grid: chunk c's blocks share residue mod 8 -> one XCD owns
// c's 200KB cmabs row (heuristic; correctness mapping-independent).

__launch_bounds__(256)
__global__ void scatter_kernel(const int* __restrict__ row, const int* __restrict__ col,
                               const float* __restrict__ vA, const float* __restrict__ vZ,
                               const unsigned* __restrict__ cmabs,
                               const unsigned short* __restrict__ lrank,
                               uint4* __restrict__ packed16, int E, int NB) {
    const int p = blockIdx.x;
    const int c = (p & 7) + 8 * (p >> 9);       // chunk (8 chunks / 512 blocks)
    if (c >= NB) return;
    const int o = (p >> 3) & 63;                // block within chunk (64x256=16384)
    const int e = (c << HIST_EPB_LOG) + o * 256 + threadIdx.x;
    if (e >= E) return;
    const int r = row[e];
    const int pos = (int)(cmabs[(size_t)c * NBINS + r] + (unsigned)lrank[e]);
    uint4 pk;
    pk.x = (unsigned)col[e];
    pk.y = __builtin_bit_cast(unsigned, vZ[e]);
    pk.z = __builtin_bit_cast(unsigned, vA[e]);
    pk.w = 0u;
    packed16[pos] = pk;
}

// ---------------- SpMM F=128 + MFMA gemm1: g1 = (M⊙h0)@W1 ----------------
// R19's measured-best gather: 2-edge-parallel uint2, half-wave h=lane>>5
// owns edges j+2q+h; lane reads 4 feats (8B) at ls=lane&31. shfl_xor(32)
// merges halves. Epilogue -> LDS h16[16][136] bf16. Barrier. Wave w
// computes output cols w*16..w*16+15 via 4 MFMAs.

__launch_bounds__(256)
__global__ void spmm128_g1(const uint4* __restrict__ packed16,
                           const int* __restrict__ rp, const unsigned short* __restrict__ X,
                           const float* __restrict__ AM, const float* __restrict__ Mv,
                           const float* __restrict__ bias,
                           const unsigned short* __restrict__ wt1,
                           unsigned short* __restrict__ g1, int n) {
    __shared__ __align__(16) unsigned short h16[16][136];
    const int t = threadIdx.x;
    const int lane = t & 63;
    const int w = t >> 6;
    const int h = lane >> 5;        // edge slot 0/1
    const int ls = lane & 31;       // feat quad: feats 4*ls..4*ls+3
    const int rbase = blockIdx.x * 16;

    for (int i = 0; i < 4; ++i) {
        const int lr = w * 4 + i;
        const int r = rbase + lr;
        float a0 = 0.0f, a1 = 0.0f, a2 = 0.0f, a3 = 0.0f;
        if (r < n) {
            const int s = __builtin_amdgcn_readfirstlane(rp[r]);
            const int e = __builtin_amdgcn_readfirstlane(rp[r + 1]);
            for (int base = s; base < e; base += 64) {
                const int nn = min(64, e - base);
                int ci = 0; float vf = 0.0f;
                if (lane < nn) {
                    const uint4 pk = packed16[base + lane];
                    ci = (int)pk.x;
                    vf = __builtin_bit_cast(float, pk.y);
                }
                for (int j = 0; j < nn; j += 32) {       // 16 uint2 loads in flight
                    uint2 uu[16]; float vv[16];
#pragma unroll
                    for (int q = 0; q < 16; ++q) {
                        const int jj = j + 2 * q + h;
                        const bool ok = jj < nn;
                        const int idx = jj & 63;
                        const int c = __shfl(ci, idx);
                        const float v = __shfl(vf, idx);
                        vv[q] = ok ? v : 0.0f;
                        uint2 u = make_uint2(0u, 0u);
                        if (ok) u = *(const uint2*)(X + (size_t)c * 128 + ls * 4);
                        uu[q] = u;
                    }
#pragma unroll
                    for (int q = 0; q < 16; ++q) {
                        a0 += vv[q] * bf_lo(uu[q].x);
                        a1 += vv[q] * bf_hi(uu[q].x);
                        a2 += vv[q] * bf_lo(uu[q].y);
                        a3 += vv[q] * bf_hi(uu[q].y);
                    }
                }
            }
            a0 += __shfl_xor(a0, 32);
            a1 += __shfl_xor(a1, 32);
            a2 += __shfl_xor(a2, 32);
            a3 += __shfl_xor(a3, 32);
            const float am = AM[r];
            const float mr = Mv[r];   // fold M (>=0): M⊙relu(y) = relu(M⊙y)
            a0 = fminf(fmaxf((a0 * am + bias[4 * ls + 0]) * mr, 0.0f), 1e30f);
            a1 = fminf(fmaxf((a1 * am + bias[4 * ls + 1]) * mr, 0.0f), 1e30f);
            a2 = fminf(fmaxf((a2 * am + bias[4 * ls + 2]) * mr, 0.0f), 1e30f);
            a3 = fminf(fmaxf((a3 * am + bias[4 * ls + 3]) * mr, 0.0f), 1e30f);
        }
        if (lane < 32) {
            uint2 wv;
            wv.x = pack2bf(a0, a1);
            wv.y = pack2bf(a2, a3);
            *(uint2*)&h16[lr][4 * ls] = wv;
        }
    }
    __syncthreads();

    // MFMA gemm1: wave w -> cols w*16 .. w*16+15
    const int m15 = lane & 15;
    const int q = lane >> 4;
    bf16x8 a[4];
#pragma unroll
    for (int ks = 0; ks < 4; ++ks)
        a[ks] = __builtin_bit_cast(bf16x8,
                    *(const uint4*)&h16[m15][ks * 32 + q * 8]);
    f32x4 acc = {0.f, 0.f, 0.f, 0.f};
    const int bn = w * 16 + m15;
#pragma unroll
    for (int ks = 0; ks < 4; ++ks) {
        const uint4 z = *(const uint4*)(wt1 + (size_t)bn * 128 + ks * 32 + q * 8);
        acc = __builtin_amdgcn_mfma_f32_16x16x32_bf16(
            a[ks], __builtin_bit_cast(bf16x8, z), acc, 0, 0, 0);
    }
    const int gcol = w * 16 + m15;
#pragma unroll
    for (int rr = 0; rr < 4; ++rr) {
        const int grow = rbase + q * 4 + rr;
        if (grow < n) g1[(size_t)grow * 64 + gcol] = f2bf(clampf(acc[rr]));
    }
}

// ---------------- SpMM F=64 + MFMA gemm2: out40 = relu(AM⊙agg+b1)@W2 ----------------
// R20's measured version: 8-edge-parallel uint4. Slot g8=lane>>3 owns edges
// j+8q+g8; lane reads 8 feats (16B) at ls=lane&7. xor-8/16/32 merges slots.
// lane<8 -> uint4 LDS write into h16[16][72]. Barrier. Waves 0-2 compute
// col-tiles (48 padded cols, 2 MFMAs); write cols<40.

__launch_bounds__(256)
__global__ void spmm64_g2(const uint4* __restrict__ packed16,
                          const int* __restrict__ rp, const unsigned short* __restrict__ X,
                          const float* __restrict__ AM, const float* __restrict__ bias1,
                          const unsigned short* __restrict__ wt2,
                          unsigned short* __restrict__ out40, int n) {
    __shared__ __align__(16) unsigned short h16[16][72];
    const int t = threadIdx.x;
    const int lane = t & 63;
    const int w = t >> 6;
    const int g8 = lane >> 3;       // edge slot 0..7
    const int ls = lane & 7;        // feat octet: feats 8*ls..8*ls+7
    const int rbase = blockIdx.x * 16;

    for (int i = 0; i < 4; ++i) {
        const int lr = w * 4 + i;
        const int r = rbase + lr;
        float a0 = 0.f, a1 = 0.f, a2 = 0.f, a3 = 0.f;
        float a4 = 0.f, a5 = 0.f, a6 = 0.f, a7 = 0.f;
        if (r < n) {
            const int s = __builtin_amdgcn_readfirstlane(rp[r]);
            const int e = __builtin_amdgcn_readfirstlane(rp[r + 1]);
            for (int base = s; base < e; base += 64) {
                const int nn = min(64, e - base);
                int ci = 0; float vf = 0.0f;
                if (lane < nn) {
                    const uint4 pk = packed16[base + lane];
                    ci = (int)pk.x;
                    vf = __builtin_bit_cast(float, pk.y);
                }
                for (int j = 0; j < nn; j += 32) {   // 4 uint4 loads in flight
                    uint4 uu[4]; float vv[4];
#pragma unroll
                    for (int q = 0; q < 4; ++q) {
                        const int jj = j + 8 * q + g8;
                        const bool ok = jj < nn;
                        const int idx = jj & 63;
                        const int c = __shfl(ci, idx);
                        const float v = __shfl(vf, idx);
                        vv[q] = ok ? v : 0.0f;
                        uint4 u = make_uint4(0u, 0u, 0u, 0u);
                        if (ok) u = *(const uint4*)(X + (size_t)c * 64 + ls * 8);
                        uu[q] = u;
                    }
#pragma unroll
                    for (int q = 0; q < 4; ++q) {
                        a0 += vv[q] * bf_lo(uu[q].x);
                        a1 += vv[q] * bf_hi(uu[q].x);
                        a2 += vv[q] * bf_lo(uu[q].y);
                        a3 += vv[q] * bf_hi(uu[q].y);
                        a4 += vv[q] * bf_lo(uu[q].z);
                        a5 += vv[q] * bf_hi(uu[q].z);
                        a6 += vv[q] * bf_lo(uu[q].w);
                        a7 += vv[q] * bf_hi(uu[q].w);
                    }
                }
            }
            a0 += __shfl_xor(a0, 8); a0 += __shfl_xor(a0, 16); a0 += __shfl_xor(a0, 32);
            a1 += __shfl_xor(a1, 8); a1 += __shfl_xor(a1, 16); a1 += __shfl_xor(a1, 32);
            a2 += __shfl_xor(a2, 8); a2 += __shfl_xor(a2, 16); a2 += __shfl_xor(a2, 32);
            a3 += __shfl_xor(a3, 8); a3 += __shfl_xor(a3, 16); a3 += __shfl_xor(a3, 32);
            a4 += __shfl_xor(a4, 8); a4 += __shfl_xor(a4, 16); a4 += __shfl_xor(a4, 32);
            a5 += __shfl_xor(a5, 8); a5 += __shfl_xor(a5, 16); a5 += __shfl_xor(a5, 32);
            a6 += __shfl_xor(a6, 8); a6 += __shfl_xor(a6, 16); a6 += __shfl_xor(a6, 32);
            a7 += __shfl_xor(a7, 8); a7 += __shfl_xor(a7, 16); a7 += __shfl_xor(a7, 32);
            const float am = AM[r];
            a0 = fminf(fmaxf(a0 * am + bias1[8 * ls + 0], 0.0f), 1e30f);
            a1 = fminf(fmaxf(a1 * am + bias1[8 * ls + 1], 0.0f), 1e30f);
            a2 = fminf(fmaxf(a2 * am + bias1[8 * ls + 2], 0.0f), 1e30f);
            a3 = fminf(fmaxf(a3 * am + bias1[8 * ls + 3], 0.0f), 1e30f);
            a4 = fminf(fmaxf(a4 * am + bias1[8 * ls + 4], 0.0f), 1e30f);
            a5 = fminf(fmaxf(a5 * am + bias1[8 * ls + 5], 0.0f), 1e30f);
            a6 = fminf(fmaxf(a6 * am + bias1[8 * ls + 6], 0.0f), 1e30f);
            a7 = fminf(fmaxf(a7 * am + bias1[8 * ls + 7], 0.0f), 1e30f);
        }
        if (lane < 8) {
            uint4 wv;
            wv.x = pack2bf(a0, a1);
            wv.y = pack2bf(a2, a3);
            wv.z = pack2bf(a4, a5);
            wv.w = pack2bf(a6, a7);
            *(uint4*)&h16[lr][8 * ls] = wv;
        }
    }
    __syncthreads();

    // MFMA gemm2: waves 0-2 -> col tiles 0..2 (cols 0..47, wt2 zero-padded)
    if (w < 3) {
        const int m15 = lane & 15;
        const int q = lane >> 4;
        bf16x8 a[2];
#pragma unroll
        for (int ks = 0; ks < 2; ++ks)
            a[ks] = __builtin_bit_cast(bf16x8,
                        *(const uint4*)&h16[m15][ks * 32 + q * 8]);
        f32x4 acc = {0.f, 0.f, 0.f, 0.f};
        const int bn = w * 16 + m15;
#pragma unroll
        for (int ks = 0; ks < 2; ++ks) {
            const uint4 z = *(const uint4*)(wt2 + (size_t)bn * 64 + ks * 32 + q * 8);
            acc = __builtin_amdgcn_mfma_f32_16x16x32_bf16(
                a[ks], __builtin_bit_cast(bf16x8, z), acc, 0, 0, 0);
        }
        const int gcol = w * 16 + m15;
        if (gcol < 40) {
#pragma unroll
            for (int rr = 0; rr < 4; ++rr) {
                const int grow = rbase + q * 4 + rr;
                if (grow < n) out40[(size_t)grow * 40 + gcol] = f2bf(clampf(acc[rr]));
            }
        }
    }
}

// ---------------- SpMM F=40 + log_softmax: 6 edges/wave (uint2/lane) ----------------
// R20's measured version. Slot g6=lane/10 (lanes 60-63 idle) owns edges
// j+6q+g6; lane reads 4 feats (8B) at ls=lane%10. Cyclic-6 reduce:
// b=a+rot30(a); s=b+rot10(b)+rot20(b). lane<10 -> float4 output write.

__launch_bounds__(256)
__global__ void spmm40_kernel(const uint4* __restrict__ packed16,
                              const int* __restrict__ rp, const unsigned short* __restrict__ X,
                              const float* __restrict__ bias,
                              float* __restrict__ out, int n) {
    const int lane = threadIdx.x & 63;
    const int g6 = lane / 10;
    const int ls = lane - 10 * g6;
    const bool active = g6 < 6;
    const int rot30 = (lane + 30 < 60) ? lane + 30 : lane - 30;
    const int rot10 = (lane + 10 < 60) ? lane + 10 : lane - 50;
    const int rot20 = (lane + 20 < 60) ? lane + 20 : lane - 40;
    const int r = (int)((blockIdx.x * (unsigned)blockDim.x + threadIdx.x) >> 6);
    if (r >= n) return;
    const int s = __builtin_amdgcn_readfirstlane(rp[r]);
    const int e = __builtin_amdgcn_readfirstlane(rp[r + 1]);

    float a0 = 0.f, a1 = 0.f, a2 = 0.f, a3 = 0.f;
    for (int base = s; base < e; base += 64) {
        const int nn = min(64, e - base);
        int ci = 0; float vf = 0.0f;
        if (lane < nn) {
            const uint4 pk = packed16[base + lane];
            ci = (int)pk.x;
            vf = __builtin_bit_cast(float, pk.z);    // adj (not adjZ) values
        }
        for (int j = 0; j < nn; j += 24) {   // 4 uint2 loads in flight
            uint2 uu[4]; float vv[4];
#pragma unroll
            for (int q = 0; q < 4; ++q) {
                const int jj = j + 6 * q + g6;
                const bool ok = active && jj < nn;
                const int idx = jj & 63;
                const int c = __shfl(ci, idx);
                const float v = __shfl(vf, idx);
                vv[q] = ok ? v : 0.0f;
                uint2 u = make_uint2(0u, 0u);
                if (ok) u = *(const uint2*)(X + (size_t)c * 40 + ls * 4);
                uu[q] = u;
            }
#pragma unroll
            for (int q = 0; q < 4; ++q) {
                a0 += vv[q] * bf_lo(uu[q].x);
                a1 += vv[q] * bf_hi(uu[q].x);
                a2 += vv[q] * bf_lo(uu[q].y);
                a3 += vv[q] * bf_hi(uu[q].y);
            }
        }
    }
    // cyclic-6 reduce: b(g) = a(g)+a(g+3); s(g) = b(g)+b(g+1)+b(g+2) = total
    float b0 = a0 + __shfl(a0, rot30);
    float b1 = a1 + __shfl(a1, rot30);
    float b2 = a2 + __shfl(a2, rot30);
    float b3 = a3 + __shfl(a3, rot30);
    a0 = b0 + __shfl(b0, rot10) + __shfl(b0, rot20);
    a1 = b1 + __shfl(b1, rot10) + __shfl(b1, rot20);
    a2 = b2 + __shfl(b2, rot10) + __shfl(b2, rot20);
    a3 = b3 + __shfl(b3, rot10) + __shfl(b3, rot20);

    const bool own = lane < 10;
    const float v0 = own ? fminf(fmaxf(a0 + bias[4 * ls + 0], -1e30f), 1e30f) : -INFINITY;
    const float v1 = own ? fminf(fmaxf(a1 + bias[4 * ls + 1], -1e30f), 1e30f) : -INFINITY;
    const float v2 = own ? fminf(fmaxf(a2 + bias[4 * ls + 2], -1e30f), 1e30f) : -INFINITY;
    const float v3 = own ? fminf(fmaxf(a3 + bias[4 * ls + 3], -1e30f), 1e30f) : -INFINITY;
    float mx = fmaxf(fmaxf(v0, v1), fmaxf(v2, v3));
#pragma unroll
    for (int off = 32; off > 0; off >>= 1) mx = fmaxf(mx, __shfl_xor(mx, off));
    float sum = own ? (expf(v0 - mx) + expf(v1 - mx) + expf(v2 - mx) + expf(v3 - mx))
                    : 0.0f;
#pragma unroll
    for (int off = 32; off > 0; off >>= 1) sum += __shfl_xor(sum, off);
    if (own) {
        const float lse = mx + logf(sum);
        float4 o;
        o.x = v0 - lse; o.y = v1 - lse; o.z = v2 - lse; o.w = v3 - lse;
        *(float4*)(out + (size_t)r * 40 + ls * 4) = o;
    }
}

// ---------------- launch ----------------

extern "C" void kernel_launch(void* const* d_in, const int* in_sizes, int n_in,
                              void* d_out, int out_size, void* d_ws, size_t ws_size,
                              hipStream_t stream) {
    const float* x    = (const float*)d_in[0];
    const float* M    = (const float*)d_in[1];
    const float* AM   = (const float*)d_in[2];
    const float* adjv = (const float*)d_in[3];
    const float* adjZ = (const float*)d_in[4];
    const float* W0   = (const float*)d_in[5];
    const float* b0   = (const float*)d_in[6];
    const float* W1   = (const float*)d_in[7];
    const float* b1   = (const float*)d_in[8];
    const float* W2   = (const float*)d_in[9];
    const float* b2   = (const float*)d_in[10];
    const int* row    = (const int*)d_in[11];
    const int* col    = (const int*)d_in[12];
    float* out = (float*)d_out;

    const int n = in_sizes[1];   // N  (must be <= NBINS = 50176)
    const int E = in_sizes[3];   // edges (<= NBMAX*16384)

    // workspace layout (~55 MB, NO aliasing):
    unsigned short* t_buf = (unsigned short*)d_ws;          // N*128 bf16
    unsigned short* wt1 = t_buf + (size_t)n * 128;          // 64*128
    unsigned short* wt2 = wt1 + 64 * 128;                   // 48*64
    unsigned short* h_buf = wt2 + 48 * 64;                  // N*128 bf16
    int* rp = (int*)(h_buf + (size_t)n * 128);              // N+1 (+pad)
    unsigned long long* gpub = (unsigned long long*)
        (((uintptr_t)(rp + n + 2) + 7) & ~(uintptr_t)7);    // 256 u64
    uint4* packed16 = (uint4*)
        (((uintptr_t)(gpub + 256) + 15) & ~(uintptr_t)15);  // E uint4
    unsigned short* lrank = (unsigned short*)(packed16 + (size_t)E);   // E u16
    unsigned short* cntmat = lrank + (size_t)E;             // [NBMAX][NBINS] u16
    unsigned* cmabs = (unsigned*)(cntmat + (size_t)NBMAX * NBINS);     // u32

    const int NB = (E + HIST_EPB - 1) >> HIST_EPB_LOG;      // hist chunks (<=49)
    const int gemmBlocks = (n + 63) / 64;                   // 4-wave gemm groups
    const int gemmB4 = (gemmBlocks + 3) / 4;                // 1024-thr gemm blocks
    // grid NB + gemmB4 + 1 must stay <= 256 (one block-wave at 98KB LDS)

    // fused LDS histogram + gemm0 (W0 self-transposed) + wt1/wt2/gpub prep
    hist_gemm0<<<NB + gemmB4 + 1, 1024, 0, stream>>>(row, cntmat, lrank, E, NB,
                                                     x, M, W0, W1, W2,
                                                     wt1, wt2, gpub, t_buf, n,
                                                     gemmB4);

    // one-kernel scan: rp + absolute chunk offsets (publish/read-poll)
    scan_one<<<SCAN_BLOCKS, 256, 0, stream>>>(cntmat, cmabs, rp, gpub, n, NB, E);

    // scatter, XCD-swizzled (one 16B random store per edge)
    const int scatGrid = 512 * ((NB + 7) / 8);
    scatter_kernel<<<scatGrid, 256, 0, stream>>>(row, col, adjv, adjZ,
                                                 cmabs, lrank, packed16, E, NB);

    const int blk16 = (n + 15) / 16;   // 16 rows per block

    // layer 0 aggregate + MFMA gemm1: h_buf(stride 64) = (M⊙h0)@W1
    spmm128_g1<<<blk16, 256, 0, stream>>>(packed16, rp, t_buf, AM, M, b0, wt1,
                                          h_buf, n);
    // layer 1 aggregate + MFMA gemm2: t_buf(stride 40) = relu(AM⊙agg+b1)@W2
    spmm64_g2<<<blk16, 256, 0, stream>>>(packed16, rp, h_buf, AM, b1, wt2,
                                         t_buf, n);
    // layer 2 aggregate + log_softmax
    spmm40_kernel<<<blk16 * 4, 256, 0, stream>>>(packed16, rp, t_buf, b2, out, n);
}